// Round 16
// baseline (313.605 us; speedup 1.0000x reference)
//
#include <hip/hip_runtime.h>
#include <hip/hip_bf16.h>

#define N_DIM 8192
#define E_DIM 2048
#define NKT 32           // K tiles of BK=64

typedef __bf16 bf16x8  __attribute__((ext_vector_type(8)));
typedef float  f32x4   __attribute__((ext_vector_type(4)));
typedef float  f32x16  __attribute__((ext_vector_type(16)));
typedef short  short8  __attribute__((ext_vector_type(8)));

#define GLD(gp, lp) __builtin_amdgcn_global_load_lds( \
    (const __attribute__((address_space(1))) void*)(gp), \
    (__attribute__((address_space(3))) void*)(lp), 16, 0, 0)

// ---------------- conversion: A fp32 [N,E] -> bf16 [N,E] ----------------
__global__ __launch_bounds__(256) void cvtA(const float* __restrict__ A,
                                            __hip_bfloat16* __restrict__ Abf) {
    size_t i = ((size_t)blockIdx.x * 256 + threadIdx.x) * 8;
    float4 f0 = *reinterpret_cast<const float4*>(A + i);
    float4 f1 = *reinterpret_cast<const float4*>(A + i + 4);
    union { short8 s8; __hip_bfloat16 h[8]; } u;
    u.h[0] = __float2bfloat16(f0.x);
    u.h[1] = __float2bfloat16(f0.y);
    u.h[2] = __float2bfloat16(f0.z);
    u.h[3] = __float2bfloat16(f0.w);
    u.h[4] = __float2bfloat16(f1.x);
    u.h[5] = __float2bfloat16(f1.y);
    u.h[6] = __float2bfloat16(f1.z);
    u.h[7] = __float2bfloat16(f1.w);
    *reinterpret_cast<short8*>(&Abf[i]) = u.s8;
}

// ------- scale+transpose: Bt[n,e] = W[e] * B[e,n], fp32 -> bf16 ---------
__global__ __launch_bounds__(256) void cvtB(const float* __restrict__ B,
                                            const float* __restrict__ W,
                                            __hip_bfloat16* __restrict__ Bt) {
    __shared__ float tile[32][33];
    const int tx = threadIdx.x & 31;
    const int ty = threadIdx.x >> 5;
    const int n0 = blockIdx.x * 32;
    const int e0 = blockIdx.y * 32;
#pragma unroll
    for (int r = 0; r < 4; ++r) {
        int e = e0 + ty + r * 8;
        tile[ty + r * 8][tx] = B[(size_t)e * N_DIM + n0 + tx] * W[e];
    }
    __syncthreads();
#pragma unroll
    for (int r = 0; r < 4; ++r) {
        int n = n0 + ty + r * 8;
        Bt[(size_t)n * E_DIM + e0 + tx] = __float2bfloat16(tile[tx][ty + r * 8]);
    }
}

// ---------------- GEMM: C[N,N] = Abf[N,E] * Btbf[N,E]^T ----------------
// 32x32x16 MFMA K-loop with an LDS layout byte-shape-identical to R12's
// measured-ZERO-conflict pattern: per ds_read_b128, 16 phys rows at
// stride 128B, 4 lanes per row covering one contiguous 64B window with a
// row-dependent chunk XOR perm. Per 32-row m-block (4 KB = 32 rows x 128B):
//   read:  p = (r31&15) + ((KS>>1)<<4);  w = ((r31>>4)<<1)|hi;
//          c = ((KS&1)<<2) | (w ^ ((r31>>1)&3));  addr = p*128 + c*16
// GLD dest linear (tid*16); global source applies the inverse map.
// Direct full-line nt-store epilogue (no LDS).

template<int KS, bool STGA, bool STGB, bool VMD>
__device__ __forceinline__ void phase(
    const char* Acur, const char* Bcur,
    char* Anxt, char* Bnxt,
    const char* aP, const char* bP,
    int tid, int wm, int wn, int r31, int hi,
    f32x16 (&acc)[4][2])
{
    bf16x8 af[4], bf[2];
    const int p   = (r31 & 15) + ((KS >> 1) << 4);
    const int w   = ((r31 >> 4) << 1) | hi;
    const int c   = ((KS & 1) << 2) | (w ^ ((r31 >> 1) & 3));
    const int fro = p * 128 + c * 16;
#pragma unroll
    for (int m = 0; m < 4; ++m)
        af[m] = *reinterpret_cast<const bf16x8*>(Acur + (wm * 4 + m) * 4096 + fro);
#pragma unroll
    for (int n = 0; n < 2; ++n)
        bf[n] = *reinterpret_cast<const bf16x8*>(Bcur + (wn * 2 + n) * 4096 + fro);
    if (STGA) {
#pragma unroll
        for (int q = 0; q < 4; ++q)
            GLD(aP + (size_t)q * 262144, Anxt + q * 8192 + tid * 16);
    }
    if (STGB) {
#pragma unroll
        for (int q = 0; q < 4; ++q)
            GLD(bP + (size_t)q * 262144, Bnxt + q * 8192 + tid * 16);
    }
    __builtin_amdgcn_sched_barrier(0);
    __builtin_amdgcn_s_barrier();
    asm volatile("s_waitcnt lgkmcnt(0)" ::: "memory");
    __builtin_amdgcn_sched_barrier(0);
    __builtin_amdgcn_s_setprio(1);
#pragma unroll
    for (int m = 0; m < 4; ++m)
#pragma unroll
        for (int n = 0; n < 2; ++n)
            acc[m][n] = __builtin_amdgcn_mfma_f32_32x32x16_bf16(
                af[m], bf[n], acc[m][n], 0, 0, 0);
    __builtin_amdgcn_s_setprio(0);
    __builtin_amdgcn_sched_barrier(0);
    if (VMD) asm volatile("s_waitcnt vmcnt(0)" ::: "memory");
    __builtin_amdgcn_s_barrier();
}

template<bool STG>
__device__ __forceinline__ void ktile(
    const char* Acur, const char* Bcur, char* Anxt, char* Bnxt,
    const char*& aP, const char*& bP,
    int tid, int wm, int wn, int r31, int hi,
    f32x16 (&acc)[4][2])
{
    phase<0, STG,  false, false>(Acur, Bcur, Anxt, Bnxt, aP, bP, tid, wm, wn, r31, hi, acc);
    phase<1, false, STG,  false>(Acur, Bcur, Anxt, Bnxt, aP, bP, tid, wm, wn, r31, hi, acc);
    if (STG) { aP += 128; bP += 128; }
    phase<2, false, false, false>(Acur, Bcur, Anxt, Bnxt, aP, bP, tid, wm, wn, r31, hi, acc);
    phase<3, false, false, true >(Acur, Bcur, Anxt, Bnxt, aP, bP, tid, wm, wn, r31, hi, acc);
}

__global__ __launch_bounds__(512, 2) void gemm_bt(const __hip_bfloat16* __restrict__ A,
                                                  const __hip_bfloat16* __restrict__ B,
                                                  float* __restrict__ C) {
    __shared__ __align__(16) char lds[131072];
    char* ldsA = (char*)lds;            // 2 buffers x 32 KiB
    char* ldsB = (char*)lds + 65536;    // 2 buffers x 32 KiB

    const int tid  = threadIdx.x;
    const int lane = tid & 63;
    const int wave = tid >> 6;
    const int wm = wave >> 2;          // 0..1
    const int wn = wave & 3;           // 0..3
    const int r31 = lane & 31;         // fragment row within 32
    const int hi  = lane >> 5;         // k-half selector

    // XCD-column mapping (FETCH-verified): XCD owns 4 tile-columns.
    const int bid = blockIdx.x;
    const int xcd = bid & 7;
    const int sub = (bid >> 3) & 3;
    const int tm  = bid >> 5;          // 0..31
    const int tn  = xcd * 4 + sub;     // 0..31

    // staging source = inverse of the layout map (rule 21), round-trip verified:
    //   rlow=(tid>>3)&15; KS=((tid>>7)&1)<<1 | ((tid&7)>>2);
    //   w=(tid&3)^((rlow>>1)&3); r31s=rlow+((w>>1)<<4);
    //   rloc=((tid>>8)&1)*32+r31s; qk=(KS<<1)|(w&1)
    const int rlow = (tid >> 3) & 15;
    const int KSs  = (((tid >> 7) & 1) << 1) | ((tid & 7) >> 2);
    const int ws   = (tid & 3) ^ ((rlow >> 1) & 3);
    const int r31s = rlow + ((ws >> 1) << 4);
    const int rloc = ((tid >> 8) & 1) * 32 + r31s;
    const int qk   = (KSs << 1) | (ws & 1);
    const char* aP = (const char*)A +
        (((size_t)tm * 256 + rloc) * E_DIM + qk * 8) * 2;
    const char* bP = (const char*)B +
        (((size_t)tn * 256 + rloc) * E_DIM + qk * 8) * 2;

    // prologue: stage tile 0 into buffer 0
#pragma unroll
    for (int q = 0; q < 4; ++q) {
        GLD(aP + (size_t)q * 262144, ldsA + q * 8192 + tid * 16);
        GLD(bP + (size_t)q * 262144, ldsB + q * 8192 + tid * 16);
    }
    aP += 128; bP += 128;
    asm volatile("s_waitcnt vmcnt(0)" ::: "memory");
    __builtin_amdgcn_s_barrier();

    f32x16 acc[4][2] = {};

    for (int it = 0; it < NKT / 2 - 1; ++it) {
        ktile<true>(ldsA,         ldsB,         ldsA + 32768, ldsB + 32768,
                    aP, bP, tid, wm, wn, r31, hi, acc);
        ktile<true>(ldsA + 32768, ldsB + 32768, ldsA,         ldsB,
                    aP, bP, tid, wm, wn, r31, hi, acc);
    }
    ktile<true >(ldsA,         ldsB,         ldsA + 32768, ldsB + 32768,
                 aP, bP, tid, wm, wn, r31, hi, acc);
    ktile<false>(ldsA + 32768, ldsB + 32768, ldsA,         ldsB,
                 aP, bP, tid, wm, wn, r31, hi, acc);

    // ---- epilogue: direct full-line nontemporal stores, no LDS.
    // 32x32 C/D layout (m74/m101): col = lane&31, row = (r&3)+8*(r>>2)+4*hi.
    const int crow = tm * 256 + wm * 128 + 4 * hi;
    const int ccol = tn * 256 + wn * 64 + r31;
#pragma unroll
    for (int m = 0; m < 4; ++m)
#pragma unroll
        for (int n = 0; n < 2; ++n)
#pragma unroll
            for (int r = 0; r < 16; ++r) {
                const int row = crow + m * 32 + (r & 3) + 8 * (r >> 2);
                __builtin_nontemporal_store(acc[m][n][r],
                    &C[(size_t)row * N_DIM + ccol + n * 32]);
            }
}

extern "C" void kernel_launch(void* const* d_in, const int* in_sizes, int n_in,
                              void* d_out, int out_size, void* d_ws, size_t ws_size,
                              hipStream_t stream) {
    const float* A = (const float*)d_in[0];   // DV2_H        [N, E]
    const float* B = (const float*)d_in[1];   // invDE_HT_DV2 [E, N]
    const float* W = (const float*)d_in[2];   // W            [E]
    float* C = (float*)d_out;                 // G            [N, N] fp32

    __hip_bfloat16* Abf  = (__hip_bfloat16*)d_ws;               // 32 MB
    __hip_bfloat16* Btbf = Abf + (size_t)N_DIM * E_DIM;         // 32 MB

    cvtA<<<(N_DIM * (size_t)E_DIM) / 8 / 256, 256, 0, stream>>>(A, Abf);
    dim3 tgrid(N_DIM / 32, E_DIM / 32);
    cvtB<<<tgrid, 256, 0, stream>>>(B, W, Btbf);
    gemm_bt<<<(N_DIM / 256) * (N_DIM / 256), 512, 0, stream>>>(Abf, Btbf, C);
}

// Round 17
// 312.233 us; speedup vs baseline: 1.0044x; 1.0044x over previous
//
#include <hip/hip_runtime.h>
#include <hip/hip_bf16.h>

#define N_DIM 8192
#define E_DIM 2048
#define NKT 32           // K tiles of BK=64

typedef __bf16 bf16x8  __attribute__((ext_vector_type(8)));
typedef float  f32x4   __attribute__((ext_vector_type(4)));
typedef float  f32x16  __attribute__((ext_vector_type(16)));
typedef short  short8  __attribute__((ext_vector_type(8)));

#define GLD(gp, lp) __builtin_amdgcn_global_load_lds( \
    (const __attribute__((address_space(1))) void*)(gp), \
    (__attribute__((address_space(3))) void*)(lp), 16, 0, 0)

// ---------------- conversion: A fp32 [N,E] -> bf16 [N,E] ----------------
__global__ __launch_bounds__(256) void cvtA(const float* __restrict__ A,
                                            __hip_bfloat16* __restrict__ Abf) {
    size_t i = ((size_t)blockIdx.x * 256 + threadIdx.x) * 8;
    float4 f0 = *reinterpret_cast<const float4*>(A + i);
    float4 f1 = *reinterpret_cast<const float4*>(A + i + 4);
    union { short8 s8; __hip_bfloat16 h[8]; } u;
    u.h[0] = __float2bfloat16(f0.x);
    u.h[1] = __float2bfloat16(f0.y);
    u.h[2] = __float2bfloat16(f0.z);
    u.h[3] = __float2bfloat16(f0.w);
    u.h[4] = __float2bfloat16(f1.x);
    u.h[5] = __float2bfloat16(f1.y);
    u.h[6] = __float2bfloat16(f1.z);
    u.h[7] = __float2bfloat16(f1.w);
    *reinterpret_cast<short8*>(&Abf[i]) = u.s8;
}

// ------- scale+transpose: Bt[n,e] = W[e] * B[e,n], fp32 -> bf16 ---------
__global__ __launch_bounds__(256) void cvtB(const float* __restrict__ B,
                                            const float* __restrict__ W,
                                            __hip_bfloat16* __restrict__ Bt) {
    __shared__ float tile[32][33];
    const int tx = threadIdx.x & 31;
    const int ty = threadIdx.x >> 5;
    const int n0 = blockIdx.x * 32;
    const int e0 = blockIdx.y * 32;
#pragma unroll
    for (int r = 0; r < 4; ++r) {
        int e = e0 + ty + r * 8;
        tile[ty + r * 8][tx] = B[(size_t)e * N_DIM + n0 + tx] * W[e];
    }
    __syncthreads();
#pragma unroll
    for (int r = 0; r < 4; ++r) {
        int n = n0 + ty + r * 8;
        Bt[(size_t)n * E_DIM + e0 + tx] = __float2bfloat16(tile[tx][ty + r * 8]);
    }
}

// ---------------- GEMM: C[N,N] = Abf[N,E] * Btbf[N,E]^T ----------------
// 32x32x16 MFMA K-loop. LDS layout with ROW-PARITY bank-half flip so each
// 16-lane issue group covers all 32 banks with <=2 rows per bank-quad —
// byte-shape-identical to R12's measured-ZERO pattern. Per 32-row m-block
// (4 KB), chunk (p,c) [p=row 0..31, c=16B chunk 0..7]:
//   p = (r31&15) | ((KS>>1)<<4);  w = ((r31>>4)<<1)|hi;
//   c = (((KS&1) ^ (r31&1)) << 2) | (w ^ ((r31>>1)&3))
// GLD dest linear (tid*16); global source applies the inverse map.
// Direct full-line nt-store epilogue (no LDS).

template<int KS, bool STGA, bool STGB, bool VMD>
__device__ __forceinline__ void phase(
    const char* Acur, const char* Bcur,
    char* Anxt, char* Bnxt,
    const char* aP, const char* bP,
    int tid, int wm, int wn, int r31, int hi,
    f32x16 (&acc)[4][2])
{
    bf16x8 af[4], bf[2];
    const int p   = (r31 & 15) + ((KS >> 1) << 4);
    const int w   = ((r31 >> 4) << 1) | hi;
    const int c   = (((KS & 1) ^ (r31 & 1)) << 2) | (w ^ ((r31 >> 1) & 3));
    const int fro = p * 128 + c * 16;
#pragma unroll
    for (int m = 0; m < 4; ++m)
        af[m] = *reinterpret_cast<const bf16x8*>(Acur + (wm * 4 + m) * 4096 + fro);
#pragma unroll
    for (int n = 0; n < 2; ++n)
        bf[n] = *reinterpret_cast<const bf16x8*>(Bcur + (wn * 2 + n) * 4096 + fro);
    if (STGA) {
#pragma unroll
        for (int q = 0; q < 4; ++q)
            GLD(aP + (size_t)q * 262144, Anxt + q * 8192 + tid * 16);
    }
    if (STGB) {
#pragma unroll
        for (int q = 0; q < 4; ++q)
            GLD(bP + (size_t)q * 262144, Bnxt + q * 8192 + tid * 16);
    }
    __builtin_amdgcn_sched_barrier(0);
    __builtin_amdgcn_s_barrier();
    asm volatile("s_waitcnt lgkmcnt(0)" ::: "memory");
    __builtin_amdgcn_sched_barrier(0);
    __builtin_amdgcn_s_setprio(1);
#pragma unroll
    for (int m = 0; m < 4; ++m)
#pragma unroll
        for (int n = 0; n < 2; ++n)
            acc[m][n] = __builtin_amdgcn_mfma_f32_32x32x16_bf16(
                af[m], bf[n], acc[m][n], 0, 0, 0);
    __builtin_amdgcn_s_setprio(0);
    __builtin_amdgcn_sched_barrier(0);
    if (VMD) asm volatile("s_waitcnt vmcnt(0)" ::: "memory");
    __builtin_amdgcn_s_barrier();
}

template<bool STG>
__device__ __forceinline__ void ktile(
    const char* Acur, const char* Bcur, char* Anxt, char* Bnxt,
    const char*& aP, const char*& bP,
    int tid, int wm, int wn, int r31, int hi,
    f32x16 (&acc)[4][2])
{
    phase<0, STG,  false, false>(Acur, Bcur, Anxt, Bnxt, aP, bP, tid, wm, wn, r31, hi, acc);
    phase<1, false, STG,  false>(Acur, Bcur, Anxt, Bnxt, aP, bP, tid, wm, wn, r31, hi, acc);
    if (STG) { aP += 128; bP += 128; }
    phase<2, false, false, false>(Acur, Bcur, Anxt, Bnxt, aP, bP, tid, wm, wn, r31, hi, acc);
    phase<3, false, false, true >(Acur, Bcur, Anxt, Bnxt, aP, bP, tid, wm, wn, r31, hi, acc);
}

__global__ __launch_bounds__(512, 2) void gemm_bt(const __hip_bfloat16* __restrict__ A,
                                                  const __hip_bfloat16* __restrict__ B,
                                                  float* __restrict__ C) {
    __shared__ __align__(16) char lds[131072];
    char* ldsA = (char*)lds;            // 2 buffers x 32 KiB
    char* ldsB = (char*)lds + 65536;    // 2 buffers x 32 KiB

    const int tid  = threadIdx.x;
    const int lane = tid & 63;
    const int wave = tid >> 6;
    const int wm = wave >> 2;          // 0..1
    const int wn = wave & 3;           // 0..3
    const int r31 = lane & 31;         // fragment row within 32
    const int hi  = lane >> 5;         // k-half selector

    // XCD-column mapping (FETCH-verified): XCD owns 4 tile-columns.
    const int bid = blockIdx.x;
    const int xcd = bid & 7;
    const int sub = (bid >> 3) & 3;
    const int tm  = bid >> 5;          // 0..31
    const int tn  = xcd * 4 + sub;     // 0..31

    // staging source = inverse of the layout map (rule 21):
    //   p=(tid>>3)&31; c=tid&7;
    //   KS = ((p>>4)<<1) | ((c>>2) ^ (p&1));
    //   w  = (c&3) ^ ((p>>1)&3);
    //   r31= (p&15) | ((w>>1)<<4);  hi = w&1;
    //   rloc = ((tid>>8)&1)*32 + r31;  qk = (KS<<1)|hi
    const int p_   = (tid >> 3) & 31;
    const int c_   = tid & 7;
    const int KSs  = ((p_ >> 4) << 1) | ((c_ >> 2) ^ (p_ & 1));
    const int ws   = (c_ & 3) ^ ((p_ >> 1) & 3);
    const int r31s = (p_ & 15) | ((ws >> 1) << 4);
    const int rloc = ((tid >> 8) & 1) * 32 + r31s;
    const int qk   = (KSs << 1) | (ws & 1);
    const char* aP = (const char*)A +
        (((size_t)tm * 256 + rloc) * E_DIM + qk * 8) * 2;
    const char* bP = (const char*)B +
        (((size_t)tn * 256 + rloc) * E_DIM + qk * 8) * 2;

    // prologue: stage tile 0 into buffer 0
#pragma unroll
    for (int q = 0; q < 4; ++q) {
        GLD(aP + (size_t)q * 262144, ldsA + q * 8192 + tid * 16);
        GLD(bP + (size_t)q * 262144, ldsB + q * 8192 + tid * 16);
    }
    aP += 128; bP += 128;
    asm volatile("s_waitcnt vmcnt(0)" ::: "memory");
    __builtin_amdgcn_s_barrier();

    f32x16 acc[4][2] = {};

    for (int it = 0; it < NKT / 2 - 1; ++it) {
        ktile<true>(ldsA,         ldsB,         ldsA + 32768, ldsB + 32768,
                    aP, bP, tid, wm, wn, r31, hi, acc);
        ktile<true>(ldsA + 32768, ldsB + 32768, ldsA,         ldsB,
                    aP, bP, tid, wm, wn, r31, hi, acc);
    }
    ktile<true >(ldsA,         ldsB,         ldsA + 32768, ldsB + 32768,
                 aP, bP, tid, wm, wn, r31, hi, acc);
    ktile<false>(ldsA + 32768, ldsB + 32768, ldsA,         ldsB,
                 aP, bP, tid, wm, wn, r31, hi, acc);

    // ---- epilogue: direct full-line nontemporal stores, no LDS.
    // 32x32 C/D layout (m74/m101): col = lane&31, row = (r&3)+8*(r>>2)+4*hi.
    const int crow = tm * 256 + wm * 128 + 4 * hi;
    const int ccol = tn * 256 + wn * 64 + r31;
#pragma unroll
    for (int m = 0; m < 4; ++m)
#pragma unroll
        for (int n = 0; n < 2; ++n)
#pragma unroll
            for (int r = 0; r < 16; ++r) {
                const int row = crow + m * 32 + (r & 3) + 8 * (r >> 2);
                __builtin_nontemporal_store(acc[m][n][r],
                    &C[(size_t)row * N_DIM + ccol + n * 32]);
            }
}

extern "C" void kernel_launch(void* const* d_in, const int* in_sizes, int n_in,
                              void* d_out, int out_size, void* d_ws, size_t ws_size,
                              hipStream_t stream) {
    const float* A = (const float*)d_in[0];   // DV2_H        [N, E]
    const float* B = (const float*)d_in[1];   // invDE_HT_DV2 [E, N]
    const float* W = (const float*)d_in[2];   // W            [E]
    float* C = (float*)d_out;                 // G            [N, N] fp32

    __hip_bfloat16* Abf  = (__hip_bfloat16*)d_ws;               // 32 MB
    __hip_bfloat16* Btbf = Abf + (size_t)N_DIM * E_DIM;         // 32 MB

    cvtA<<<(N_DIM * (size_t)E_DIM) / 8 / 256, 256, 0, stream>>>(A, Abf);
    dim3 tgrid(N_DIM / 32, E_DIM / 32);
    cvtB<<<tgrid, 256, 0, stream>>>(B, W, Btbf);
    gemm_bt<<<(N_DIM / 256) * (N_DIM / 256), 512, 0, stream>>>(Abf, Btbf, C);
}

// Round 18
// 278.960 us; speedup vs baseline: 1.1242x; 1.1193x over previous
//
#include <hip/hip_runtime.h>
#include <hip/hip_bf16.h>

#define N_DIM 8192
#define E_DIM 2048
#define NKT 32           // K tiles of BK=64

typedef __bf16 bf16x8 __attribute__((ext_vector_type(8)));
typedef float  f32x4  __attribute__((ext_vector_type(4)));
typedef short  short8 __attribute__((ext_vector_type(8)));

#define GLD(gp, lp) __builtin_amdgcn_global_load_lds( \
    (const __attribute__((address_space(1))) void*)(gp), \
    (__attribute__((address_space(3))) void*)(lp), 16, 0, 0)

// ---------------- conversion: A fp32 [N,E] -> bf16 [N,E] ----------------
__global__ __launch_bounds__(256) void cvtA(const float* __restrict__ A,
                                            __hip_bfloat16* __restrict__ Abf) {
    size_t i = ((size_t)blockIdx.x * 256 + threadIdx.x) * 8;
    float4 f0 = *reinterpret_cast<const float4*>(A + i);
    float4 f1 = *reinterpret_cast<const float4*>(A + i + 4);
    union { short8 s8; __hip_bfloat16 h[8]; } u;
    u.h[0] = __float2bfloat16(f0.x);
    u.h[1] = __float2bfloat16(f0.y);
    u.h[2] = __float2bfloat16(f0.z);
    u.h[3] = __float2bfloat16(f0.w);
    u.h[4] = __float2bfloat16(f1.x);
    u.h[5] = __float2bfloat16(f1.y);
    u.h[6] = __float2bfloat16(f1.z);
    u.h[7] = __float2bfloat16(f1.w);
    *reinterpret_cast<short8*>(&Abf[i]) = u.s8;
}

// ------- scale+transpose: Bt[n,e] = W[e] * B[e,n], fp32 -> bf16 ---------
__global__ __launch_bounds__(256) void cvtB(const float* __restrict__ B,
                                            const float* __restrict__ W,
                                            __hip_bfloat16* __restrict__ Bt) {
    __shared__ float tile[32][33];
    const int tx = threadIdx.x & 31;
    const int ty = threadIdx.x >> 5;
    const int n0 = blockIdx.x * 32;
    const int e0 = blockIdx.y * 32;
#pragma unroll
    for (int r = 0; r < 4; ++r) {
        int e = e0 + ty + r * 8;
        tile[ty + r * 8][tx] = B[(size_t)e * N_DIM + n0 + tx] * W[e];
    }
    __syncthreads();
#pragma unroll
    for (int r = 0; r < 4; ++r) {
        int n = n0 + ty + r * 8;
        Bt[(size_t)n * E_DIM + e0 + tx] = __float2bfloat16(tile[tx][ty + r * 8]);
    }
}

// ---------------- GEMM: C[N,N] = Abf[N,E] * Btbf[N,E]^T ----------------
// Best verified configuration (R12): 256x256 tile, BK=64, 8 waves (2Mx4N,
// 128x64 each), 2 LDS buffers, 4 fine phases per K-tile, 8-slot XOR
// swizzle, 16x16x32 MFMA, XCD-column mapping (B slice 4 MB = L2-resident,
// FETCH-verified 540->197 MB), LDS-band epilogue with full-line nt-stores.

template<bool RDA, bool RDB, int MH, int NP, bool STGA, bool STGB, bool VMD>
__device__ __forceinline__ void phase(
    const char* Acur, const char* Bcur,
    char* Anxt, char* Bnxt,
    const char* aP, const char* bP,
    int tid, int wm, int wn, int fr, int kq,
    bf16x8 (&af)[4][2], bf16x8 (&bf)[4][2], f32x4 (&acc)[8][4])
{
    if (RDA) {
#pragma unroll
        for (int f = 0; f < 4; ++f)
#pragma unroll
            for (int h = 0; h < 2; ++h) {
                const int row = wm * 128 + (MH * 4 + f) * 16 + fr;
                af[f][h] = *reinterpret_cast<const bf16x8*>(
                    Acur + row * 128 + ((((h << 2) | kq) ^ (fr & 7)) * 16));
            }
    }
    if (RDB) {
#pragma unroll
        for (int n = 0; n < 2; ++n)
#pragma unroll
            for (int h = 0; h < 2; ++h) {
                const int row = wn * 64 + (NP * 2 + n) * 16 + fr;
                bf[NP * 2 + n][h] = *reinterpret_cast<const bf16x8*>(
                    Bcur + row * 128 + ((((h << 2) | kq) ^ (fr & 7)) * 16));
            }
    }
    if (STGA) {
#pragma unroll
        for (int q = 0; q < 4; ++q)
            GLD(aP + (size_t)q * 262144, Anxt + q * 8192 + tid * 16);
    }
    if (STGB) {
#pragma unroll
        for (int q = 0; q < 4; ++q)
            GLD(bP + (size_t)q * 262144, Bnxt + q * 8192 + tid * 16);
    }
    __builtin_amdgcn_sched_barrier(0);
    __builtin_amdgcn_s_barrier();
    asm volatile("s_waitcnt lgkmcnt(0)" ::: "memory");
    __builtin_amdgcn_sched_barrier(0);
    __builtin_amdgcn_s_setprio(1);
#pragma unroll
    for (int f = 0; f < 4; ++f)
#pragma unroll
        for (int n = 0; n < 2; ++n)
#pragma unroll
            for (int h = 0; h < 2; ++h)
                acc[MH * 4 + f][NP * 2 + n] = __builtin_amdgcn_mfma_f32_16x16x32_bf16(
                    af[f][h], bf[NP * 2 + n][h], acc[MH * 4 + f][NP * 2 + n], 0, 0, 0);
    __builtin_amdgcn_s_setprio(0);
    __builtin_amdgcn_sched_barrier(0);
    if (VMD) asm volatile("s_waitcnt vmcnt(0)" ::: "memory");
    __builtin_amdgcn_s_barrier();
}

template<bool STG>
__device__ __forceinline__ void ktile(
    const char* Acur, const char* Bcur, char* Anxt, char* Bnxt,
    const char*& aP, const char*& bP,
    int tid, int wm, int wn, int fr, int kq,
    bf16x8 (&af)[4][2], bf16x8 (&bf)[4][2], f32x4 (&acc)[8][4])
{
    phase<true,  true,  0, 0, STG,  false, false>(Acur, Bcur, Anxt, Bnxt, aP, bP,
        tid, wm, wn, fr, kq, af, bf, acc);
    phase<false, true,  0, 1, false, STG,  false>(Acur, Bcur, Anxt, Bnxt, aP, bP,
        tid, wm, wn, fr, kq, af, bf, acc);
    if (STG) { aP += 128; bP += 128; }
    phase<true,  false, 1, 0, false, false, false>(Acur, Bcur, Anxt, Bnxt, aP, bP,
        tid, wm, wn, fr, kq, af, bf, acc);
    phase<false, false, 1, 1, false, false, true >(Acur, Bcur, Anxt, Bnxt, aP, bP,
        tid, wm, wn, fr, kq, af, bf, acc);
}

__global__ __launch_bounds__(512, 2) void gemm_bt(const __hip_bfloat16* __restrict__ A,
                                                  const __hip_bfloat16* __restrict__ B,
                                                  float* __restrict__ C) {
    __shared__ __align__(16) char lds[131072];
    char* ldsA = (char*)lds;            // 2 buffers x 32 KiB (256 rows x 128 B)
    char* ldsB = (char*)lds + 65536;    // 2 buffers x 32 KiB

    const int tid  = threadIdx.x;
    const int lane = tid & 63;
    const int wave = tid >> 6;
    const int wm = wave >> 2;          // 0..1
    const int wn = wave & 3;           // 0..3
    const int fr = lane & 15;
    const int kq = lane >> 4;          // 0..3

    // XCD-column mapping (FETCH-verified): XCD owns 4 tile-columns
    // (B slice 4 MB = L2-resident); tm sweeps. bid = tm*32 + sub*8 + xcd.
    const int bid = blockIdx.x;
    const int xcd = bid & 7;
    const int sub = (bid >> 3) & 3;
    const int tm  = bid >> 5;          // 0..31
    const int tn  = xcd * 4 + sub;     // 0..31

    // staging source pointers (pre-swizzled k-slot, rule 21)
    const char* aP = (const char*)A +
        (((size_t)tm * 256 + (tid >> 3)) * E_DIM + ((tid & 7) ^ ((tid >> 3) & 7)) * 8) * 2;
    const char* bP = (const char*)B +
        (((size_t)tn * 256 + (tid >> 3)) * E_DIM + ((tid & 7) ^ ((tid >> 3) & 7)) * 8) * 2;

    // prologue: stage tile 0 into buffer 0
#pragma unroll
    for (int q = 0; q < 4; ++q) {
        GLD(aP + (size_t)q * 262144, ldsA + q * 8192 + tid * 16);
        GLD(bP + (size_t)q * 262144, ldsB + q * 8192 + tid * 16);
    }
    aP += 128; bP += 128;
    asm volatile("s_waitcnt vmcnt(0)" ::: "memory");
    __builtin_amdgcn_s_barrier();

    f32x4 acc[8][4] = {};
    bf16x8 af[4][2], bf[4][2];

    for (int it = 0; it < NKT / 2 - 1; ++it) {
        ktile<true>(ldsA,         ldsB,         ldsA + 32768, ldsB + 32768,
                    aP, bP, tid, wm, wn, fr, kq, af, bf, acc);
        ktile<true>(ldsA + 32768, ldsB + 32768, ldsA,         ldsB,
                    aP, bP, tid, wm, wn, fr, kq, af, bf, acc);
    }
    ktile<true >(ldsA,         ldsB,         ldsA + 32768, ldsB + 32768,
                 aP, bP, tid, wm, wn, fr, kq, af, bf, acc);
    ktile<false>(ldsA + 32768, ldsB + 32768, ldsA,         ldsB,
                 aP, bP, tid, wm, wn, fr, kq, af, bf, acc);

    // ---- epilogue: per 64-row band, transpose through LDS, then stream out
    // full-line nontemporal f32x4 stores (64 threads x 16B = 1 KiB per row).
    float* bandbuf = (float*)lds;      // 64 KiB = 64 rows x 256 cols x 4B
    const int q4 = (lane >> 4) * 4;
#pragma unroll
    for (int b = 0; b < 4; ++b) {
        __syncthreads();               // K-loop reads / previous band stores done
        if (wm == (b >> 1)) {
            const int mi0 = (b & 1) * 4;
#pragma unroll
            for (int m = 0; m < 4; ++m)
#pragma unroll
                for (int ni = 0; ni < 4; ++ni)
#pragma unroll
                    for (int j = 0; j < 4; ++j)
                        bandbuf[(m * 16 + q4 + j) * 256 + wn * 64 + ni * 16 + fr] =
                            acc[mi0 + m][ni][j];
        }
        __syncthreads();
        const int rbase = tid >> 6;        // 0..7
        const int c4 = (tid & 63) * 4;     // col in floats
#pragma unroll
        for (int r8 = 0; r8 < 8; ++r8) {
            const int row = r8 * 8 + rbase;
            f32x4 v = *reinterpret_cast<const f32x4*>(&bandbuf[row * 256 + c4]);
            __builtin_nontemporal_store(v, reinterpret_cast<f32x4*>(
                &C[(size_t)(tm * 256 + b * 64 + row) * N_DIM + tn * 256 + c4]));
        }
    }
}

extern "C" void kernel_launch(void* const* d_in, const int* in_sizes, int n_in,
                              void* d_out, int out_size, void* d_ws, size_t ws_size,
                              hipStream_t stream) {
    const float* A = (const float*)d_in[0];   // DV2_H        [N, E]
    const float* B = (const float*)d_in[1];   // invDE_HT_DV2 [E, N]
    const float* W = (const float*)d_in[2];   // W            [E]
    float* C = (float*)d_out;                 // G            [N, N] fp32

    __hip_bfloat16* Abf  = (__hip_bfloat16*)d_ws;               // 32 MB
    __hip_bfloat16* Btbf = Abf + (size_t)N_DIM * E_DIM;         // 32 MB

    cvtA<<<(N_DIM * (size_t)E_DIM) / 8 / 256, 256, 0, stream>>>(A, Abf);
    dim3 tgrid(N_DIM / 32, E_DIM / 32);
    cvtB<<<tgrid, 256, 0, stream>>>(B, W, Btbf);
    gemm_bt<<<(N_DIM / 256) * (N_DIM / 256), 512, 0, stream>>>(Abf, Btbf, C);
}